// Round 9
// baseline (807.347 us; speedup 1.0000x reference)
//
#include <hip/hip_runtime.h>
#include <hip/hip_bf16.h>

#define T_SEQ   512
#define H_DIM   128
#define N3H     384
#define HSW     128   // h row stride (ushort): 256B rows + 16B-chunk XOR swizzle
#define XS      72    // x row stride (ushort): 144B

typedef float f32x4 __attribute__((ext_vector_type(4)));
typedef float f32x2 __attribute__((ext_vector_type(2)));
typedef float f32x4u __attribute__((ext_vector_type(4), aligned(4)));
typedef __bf16 bf16x8 __attribute__((ext_vector_type(8)));
typedef unsigned short us8 __attribute__((ext_vector_type(8)));
typedef unsigned short us4 __attribute__((ext_vector_type(4)));

#define SCL0 (-1.4426950408889634f)   // -1/ln2 (z, r)
#define SCL2 ( 2.8853900817779268f)   // +2/ln2 (hh)

static __device__ __forceinline__ unsigned short f2bf(float f) {
    unsigned int u = __builtin_bit_cast(unsigned int, f);
    u += 0x7FFFu + ((u >> 16) & 1u);
    return (unsigned short)(u >> 16);
}

// LDS-only barrier: lgkmcnt(0), vmcnt untouched -> global prefetch loads
// stay in flight across it.
static __device__ __forceinline__ void lds_barrier() {
    asm volatile("" ::: "memory");
    __builtin_amdgcn_s_waitcnt(0xC07F);
    __builtin_amdgcn_s_barrier();
    asm volatile("" ::: "memory");
}

static __device__ __forceinline__ bf16x8 ld8(const unsigned short* p) {
    return __builtin_bit_cast(bf16x8, *(const us8*)p);
}

// 16 blocks x 512 threads (8 waves).  Each block interleaves TWO independent
// 16-row GRU chains (batch tiles 2*bi, 2*bi+1) under ONE barrier per step:
// tile1's work fills tile0's latency bubbles (ds_read ~120cy, MFMA chain,
// 4-deep transcendental chain, ds_write) and vice versa.  Weights shared.
// Wave w owns N-tiles {w, 8+w, 16+w} of both chains (gates wave-local).
__global__ __launch_bounds__(512, 1) void gru_fused2(
    const float* __restrict__ inputs, const float* __restrict__ Wx,
    const float* __restrict__ Wh, const float* __restrict__ bias,
    const float* __restrict__ W_state, const float* __restrict__ w1,
    const float* __restrict__ b1, const float* __restrict__ gamma,
    const float* __restrict__ beta, const float* __restrict__ mean,
    const float* __restrict__ var, const float* __restrict__ w2,
    const float* __restrict__ b2, float* __restrict__ out)
{
    __shared__ __attribute__((aligned(16))) unsigned short hb[2][2][16 * HSW]; // [tile][parity]
    __shared__ __attribute__((aligned(16))) unsigned short xb[2][2][16 * XS];  // [tile][parity]
    __shared__ float hf[32][H_DIM + 1];

    const int tid  = threadIdx.x;
    const int w    = tid >> 6;      // wave 0..7
    const int lane = tid & 63;
    const int m    = lane & 15;
    const int q    = lane >> 4;
    const int b0   = blockIdx.x * 32;

    // ---- prescaled weight B-fragments (shared by both chains) ----
    bf16x8 whB[3][4];
    bf16x8 wxB[3][2];
    float brec[3], bin[3];
#pragma unroll
    for (int g = 0; g < 3; ++g) {
        const float s = (g < 2) ? SCL0 : SCL2;
        const int col = (8 * g + w) * 16 + m;
#pragma unroll
        for (int k = 0; k < 4; ++k) {
            us8 tmp;
#pragma unroll
            for (int j = 0; j < 8; ++j) tmp[j] = f2bf(s * Wh[(32 * k + 8 * q + j) * N3H + col]);
            whB[g][k] = __builtin_bit_cast(bf16x8, tmp);
        }
#pragma unroll
        for (int k = 0; k < 2; ++k) {
            us8 tmp;
#pragma unroll
            for (int j = 0; j < 8; ++j) tmp[j] = f2bf(s * Wx[(32 * k + 8 * q + j) * N3H + col]);
            wxB[g][k] = __builtin_bit_cast(bf16x8, tmp);
        }
        bin[g]  = s * bias[col];
        brec[g] = s * bias[N3H + col];
    }

    // XOR-swizzled h offsets; rotation-free x offsets
    int hro[4], hwo[4], xro[2];
#pragma unroll
    for (int k = 0; k < 4; ++k) hro[k] = m * HSW + (((4 * k + q) ^ (m & 7)) * 8);
#pragma unroll
    for (int i = 0; i < 4; ++i) {
        const int row = 4 * q + i;
        hwo[i] = row * HSW + (((2 * w + (m >> 3)) ^ (row & 7)) * 8) + (m & 7);
    }
#pragma unroll
    for (int k = 0; k < 2; ++k) xro[k] = m * XS + 32 * k + 8 * q;

    // staging: thread -> (tile = tid>>8, row = (tid>>4)&15, cols 4sc..4sc+3)
    const int stile = tid >> 8;
    const int sr    = (tid >> 4) & 15;
    const int sc    = tid & 15;
    const int xwoff = sr * XS + sc * 4;
    const float* xsrc = inputs + ((size_t)(b0 + stile * 16 + sr) * T_SEQ) * 65 + sc * 4;

    auto xpack = [&](f32x4u v) -> us4 {
        us4 r; r[0] = f2bf(v[0]); r[1] = f2bf(v[1]); r[2] = f2bf(v[2]); r[3] = f2bf(v[3]);
        return r;
    };

    // zero h(0) of both tiles
    {
        unsigned int* p0 = (unsigned int*)hb[0][0];
        unsigned int* p1 = (unsigned int*)hb[1][0];
        for (int i = tid; i < 16 * HSW / 2; i += 512) { p0[i] = 0; p1[i] = 0; }
    }
    // stage x(0), x(1) for own tile
    {
        f32x4u v0 = *(const f32x4u*)(xsrc + 0 * 65);
        f32x4u v1 = *(const f32x4u*)(xsrc + 1 * 65);
        *(us4*)&xb[stile][0][xwoff] = xpack(v0);
        *(us4*)&xb[stile][1][xwoff] = xpack(v1);
    }
    lds_barrier();

    // xw(0) for both tiles
    f32x4 xwA0[3], xwB0[3], xwA1[3], xwB1[3];
    {
        bf16x8 xa0[2], xa1[2];
#pragma unroll
        for (int k = 0; k < 2; ++k) {
            xa0[k] = ld8(&xb[0][0][xro[k]]);
            xa1[k] = ld8(&xb[1][0][xro[k]]);
        }
#pragma unroll
        for (int g = 0; g < 3; ++g) {
            f32x4 a0 = { bin[g], bin[g], bin[g], bin[g] };
            a0 = __builtin_amdgcn_mfma_f32_16x16x32_bf16(xa0[0], wxB[g][0], a0, 0, 0, 0);
            a0 = __builtin_amdgcn_mfma_f32_16x16x32_bf16(xa0[1], wxB[g][1], a0, 0, 0, 0);
            xwA0[g] = a0;
            f32x4 a1 = { bin[g], bin[g], bin[g], bin[g] };
            a1 = __builtin_amdgcn_mfma_f32_16x16x32_bf16(xa1[0], wxB[g][0], a1, 0, 0, 0);
            a1 = __builtin_amdgcn_mfma_f32_16x16x32_bf16(xa1[1], wxB[g][1], a1, 0, 0, 0);
            xwA1[g] = a1;
        }
    }

    f32x4u pf0 = {}, pf1 = {};
    pf0 = *(const f32x4u*)(xsrc + 2 * 65);   // x(2), own tile

    f32x4 hreg0 = { 0.f, 0.f, 0.f, 0.f };
    f32x4 hreg1 = { 0.f, 0.f, 0.f, 0.f };

    auto gates = [&](const f32x4* racc, const f32x4* xw_cur, f32x4& hreg) {
        f32x4 hnew;
#pragma unroll
        for (int i = 0; i < 4; ++i) {
            const float ea = __builtin_amdgcn_exp2f(xw_cur[0][i] + racc[0][i]);
            const float eb = __builtin_amdgcn_exp2f(xw_cur[1][i] + racc[1][i]);
            const float Pa = 1.0f + ea, Pb = 1.0f + eb;
            const float D  = __builtin_amdgcn_rcpf(Pa * Pb);
            const float z  = Pb * D;
            const float r  = Pa * D;
            const float u  = fmaf(r, racc[2][i], xw_cur[2][i]);
            const float ec = __builtin_amdgcn_exp2f(u);
            const float hh = fmaf(-2.0f, __builtin_amdgcn_rcpf(1.0f + ec), 1.0f);
            hnew[i] = fmaf(z, hreg[i] - hh, hh);
        }
        hreg = hnew;
    };

    auto recmm = [&](const bf16x8* ha, f32x4* racc) {
#pragma unroll
        for (int g = 0; g < 3; ++g) {
            f32x4 a1 = { brec[g], brec[g], brec[g], brec[g] };
            a1 = __builtin_amdgcn_mfma_f32_16x16x32_bf16(ha[0], whB[g][0], a1, 0, 0, 0);
            a1 = __builtin_amdgcn_mfma_f32_16x16x32_bf16(ha[1], whB[g][1], a1, 0, 0, 0);
            f32x4 a2 = { 0.f, 0.f, 0.f, 0.f };
            a2 = __builtin_amdgcn_mfma_f32_16x16x32_bf16(ha[2], whB[g][2], a2, 0, 0, 0);
            a2 = __builtin_amdgcn_mfma_f32_16x16x32_bf16(ha[3], whB[g][3], a2, 0, 0, 0);
            racc[g] = a1 + a2;
        }
    };

    auto xwmm = [&](const bf16x8* xa, f32x4* xw_next) {
#pragma unroll
        for (int g = 0; g < 3; ++g) {
            f32x4 acc = { bin[g], bin[g], bin[g], bin[g] };
            acc = __builtin_amdgcn_mfma_f32_16x16x32_bf16(xa[0], wxB[g][0], acc, 0, 0, 0);
            acc = __builtin_amdgcn_mfma_f32_16x16x32_bf16(xa[1], wxB[g][1], acc, 0, 0, 0);
            xw_next[g] = acc;
        }
    };

    auto step = [&](int t,
                    f32x4* xw_cur0, f32x4* xw_next0,
                    f32x4* xw_cur1, f32x4* xw_next1,
                    f32x4u& pfLoad, f32x4u& pfUse,
                    const unsigned short* hcur0, unsigned short* hnxt0,
                    const unsigned short* hcur1, unsigned short* hnxt1,
                    const unsigned short* xnxt0, const unsigned short* xnxt1,
                    unsigned short* xwr0, unsigned short* xwr1) {
        // global prefetch x(t+3) for own tile — spans the barrier
        if (t <= T_SEQ - 4) pfLoad = *(const f32x4u*)(xsrc + (t + 3) * 65);

        lds_barrier();

        // issue all LDS reads for both chains up front
        bf16x8 ha0[4], ha1[4];
#pragma unroll
        for (int k = 0; k < 4; ++k) ha0[k] = ld8(&hcur0[hro[k]]);
#pragma unroll
        for (int k = 0; k < 4; ++k) ha1[k] = ld8(&hcur1[hro[k]]);
        bf16x8 xa0[2], xa1[2];
        if (t < T_SEQ - 1) {
#pragma unroll
            for (int k = 0; k < 2; ++k) {
                xa0[k] = ld8(&xnxt0[xro[k]]);
                xa1[k] = ld8(&xnxt1[xro[k]]);
            }
        }

        // rec MFMAs for both chains (independent -> interleaved by scheduler)
        f32x4 racc0[3], racc1[3];
        recmm(ha0, racc0);
        recmm(ha1, racc1);

        // gates + h writes, chain 0 then chain 1
        gates(racc0, xw_cur0, hreg0);
#pragma unroll
        for (int i = 0; i < 4; ++i) hnxt0[hwo[i]] = f2bf(hreg0[i]);
        gates(racc1, xw_cur1, hreg1);
#pragma unroll
        for (int i = 0; i < 4; ++i) hnxt1[hwo[i]] = f2bf(hreg1[i]);

        // xw(t+1) for both chains (off the h critical path)
        if (t < T_SEQ - 1) {
            xwmm(xa0, xw_next0);
            xwmm(xa1, xw_next1);
        }

        // stage x(t+2) into own tile's LDS buffer
        if (t <= T_SEQ - 3) {
            unsigned short* xwr = stile ? xwr1 : xwr0;
            *(us4*)&xwr[xwoff] = xpack(pfUse);
        }
    };

    for (int t = 0; t < T_SEQ; t += 2) {
        step(t,     xwA0, xwB0, xwA1, xwB1, pf1, pf0,
             hb[0][0], hb[0][1], hb[1][0], hb[1][1],
             xb[0][1], xb[1][1], xb[0][0], xb[1][0]);
        step(t + 1, xwB0, xwA0, xwB1, xwA1, pf0, pf1,
             hb[0][1], hb[0][0], hb[1][1], hb[1][0],
             xb[0][0], xb[1][0], xb[0][1], xb[1][1]);
    }

    // ---- fused tail: 32 rows ----
#pragma unroll
    for (int i = 0; i < 4; ++i) {
        hf[4 * q + i][16 * w + m]      = hreg0[i];
        hf[16 + 4 * q + i][16 * w + m] = hreg1[i];
    }
    __syncthreads();

    {
        const int row = tid >> 4;           // 0..31
        const int c0  = (tid & 15) * 8;
        const float sf = inputs[((size_t)(b0 + row) * T_SEQ + (T_SEQ - 1)) * 65 + 64];
        int si = (int)sf;
        si = si < 0 ? 0 : (si > 2 ? 2 : si);
#pragma unroll
        for (int c = 0; c < 8; ++c)
            hf[row][c0 + c] += W_state[si * H_DIM + c0 + c];
    }
    __syncthreads();

    {
        const int row = tid >> 4;           // 0..31
        const int c4  = (tid & 15) * 4;     // 4 output cols
        f32x4 acc = *(const f32x4*)(b1 + c4);
        for (int k = 0; k < H_DIM; ++k) {
            const float hv = hf[row][k];
            const f32x4 wv = *(const f32x4*)(w1 + k * 64 + c4);
#pragma unroll
            for (int ii = 0; ii < 4; ++ii) acc[ii] = fmaf(hv, wv[ii], acc[ii]);
        }
        const f32x4 mv = *(const f32x4*)(mean + c4);
        const f32x4 vv = *(const f32x4*)(var + c4);
        const f32x4 gv = *(const f32x4*)(gamma + c4);
        const f32x4 bv = *(const f32x4*)(beta + c4);
        const f32x4 w2v = *(const f32x4*)(w2 + c4);
        float v = 0.0f;
#pragma unroll
        for (int ii = 0; ii < 4; ++ii) {
            float a = fmaxf(acc[ii], 0.0f);
            a = (a - mv[ii]) * rsqrtf(vv[ii] + 1e-3f) * gv[ii] + bv[ii];
            v = fmaf(a, w2v[ii], v);
        }
        v += __shfl_down(v, 8);
        v += __shfl_down(v, 4);
        v += __shfl_down(v, 2);
        v += __shfl_down(v, 1);
        if ((tid & 15) == 0) out[b0 + row] = v + b2[0];
    }
}

extern "C" void kernel_launch(void* const* d_in, const int* in_sizes, int n_in,
                              void* d_out, int out_size, void* d_ws, size_t ws_size,
                              hipStream_t stream) {
    (void)in_sizes; (void)n_in; (void)out_size; (void)d_ws; (void)ws_size;
    const float* inputs  = (const float*)d_in[0];
    const float* Wx      = (const float*)d_in[1];
    const float* Wh      = (const float*)d_in[2];
    const float* bias    = (const float*)d_in[3];
    const float* W_state = (const float*)d_in[4];
    const float* w1      = (const float*)d_in[5];
    const float* b1      = (const float*)d_in[6];
    const float* gamma   = (const float*)d_in[7];
    const float* beta    = (const float*)d_in[8];
    const float* mean    = (const float*)d_in[9];
    const float* var     = (const float*)d_in[10];
    const float* w2      = (const float*)d_in[11];
    const float* b2      = (const float*)d_in[12];
    float* out = (float*)d_out;

    gru_fused2<<<16, 512, 0, stream>>>(inputs, Wx, Wh, bias, W_state, w1, b1,
                                       gamma, beta, mean, var, w2, b2, out);
}

// Round 10
// 635.517 us; speedup vs baseline: 1.2704x; 1.2704x over previous
//
#include <hip/hip_runtime.h>
#include <hip/hip_bf16.h>

#define T_SEQ   512
#define H_DIM   128
#define N3H     384
#define HSW     128   // h row stride (ushort): 256B rows + 16B-chunk XOR swizzle

typedef float f32x4 __attribute__((ext_vector_type(4)));
typedef float f32x2 __attribute__((ext_vector_type(2)));
typedef float f32x4u __attribute__((ext_vector_type(4), aligned(4)));
typedef __bf16 bf16x8 __attribute__((ext_vector_type(8)));
typedef unsigned short us8 __attribute__((ext_vector_type(8)));
typedef unsigned int u32x4 __attribute__((ext_vector_type(4)));

#define SCL0 (-1.4426950408889634f)   // -1/ln2 (z, r)
#define SCL2 ( 2.8853900817779268f)   // +2/ln2 (hh)

static __device__ __forceinline__ unsigned short f2bf(float f) {
    unsigned int u = __builtin_bit_cast(unsigned int, f);
    u += 0x7FFFu + ((u >> 16) & 1u);
    return (unsigned short)(u >> 16);
}

// pack two f32 -> two bf16 (TRUNCATED) in one v_perm_b32.
// result.low16 = a[31:16], result.high16 = b[31:16]
static __device__ __forceinline__ unsigned int pk_trunc(float a, float b) {
    return __builtin_amdgcn_perm(__builtin_bit_cast(unsigned int, a),
                                 __builtin_bit_cast(unsigned int, b),
                                 0x03020706u);
}

// LDS-only barrier: lgkmcnt(0), vmcnt untouched -> global prefetch loads
// stay in flight across it.
static __device__ __forceinline__ void lds_barrier() {
    asm volatile("" ::: "memory");
    __builtin_amdgcn_s_waitcnt(0xC07F);
    __builtin_amdgcn_s_barrier();
    asm volatile("" ::: "memory");
}

static __device__ __forceinline__ bf16x8 ld8(const unsigned short* p) {
    return __builtin_bit_cast(bf16x8, *(const us8*)p);
}

// 32 blocks x 16 batch rows x 512 threads (8 waves, 2/SIMD).
// Wave w owns N-tiles {w, 8+w, 16+w}: z/r/hh for cols [16w,16w+16) wave-local.
// x A-fragments are loaded per-lane straight from global into registers
// (period-2 double buffer, vmcnt spans the barrier; all 8 waves read the same
// 4KB tile -> L1 dedups).  Weights prescaled (z,r by -1/ln2 incl. b_in+b_rec;
// hh by +2/ln2).  Rec GEMM seeds its C operand with xw (no pre-adds).
__global__ __launch_bounds__(512, 1) void gru_fused(
    const float* __restrict__ inputs, const float* __restrict__ Wx,
    const float* __restrict__ Wh, const float* __restrict__ bias,
    const float* __restrict__ W_state, const float* __restrict__ w1,
    const float* __restrict__ b1, const float* __restrict__ gamma,
    const float* __restrict__ beta, const float* __restrict__ mean,
    const float* __restrict__ var, const float* __restrict__ w2,
    const float* __restrict__ b2, float* __restrict__ out)
{
    __shared__ __attribute__((aligned(16))) unsigned short hb[2][16 * HSW];
    __shared__ float hf[16][H_DIM + 1];

    const int tid  = threadIdx.x;
    const int w    = tid >> 6;      // wave 0..7
    const int lane = tid & 63;
    const int m    = lane & 15;
    const int q    = lane >> 4;
    const int b0   = blockIdx.x * 16;

    // ---- prescaled weight B-fragments in registers ----
    bf16x8 whB[3][4];
    bf16x8 wxB[3][2];
    float bin[3];     // z,r: s*(b_in+b_rec); hh: s*b_in  (xw C-seed)
    float brec2;      // hh:  s*b_rec                      (rec C-seed)
#pragma unroll
    for (int g = 0; g < 3; ++g) {
        const float s = (g < 2) ? SCL0 : SCL2;
        const int col = (8 * g + w) * 16 + m;
#pragma unroll
        for (int k = 0; k < 4; ++k) {
            us8 tmp;
#pragma unroll
            for (int j = 0; j < 8; ++j) tmp[j] = f2bf(s * Wh[(32 * k + 8 * q + j) * N3H + col]);
            whB[g][k] = __builtin_bit_cast(bf16x8, tmp);
        }
#pragma unroll
        for (int k = 0; k < 2; ++k) {
            us8 tmp;
#pragma unroll
            for (int j = 0; j < 8; ++j) tmp[j] = f2bf(s * Wx[(32 * k + 8 * q + j) * N3H + col]);
            wxB[g][k] = __builtin_bit_cast(bf16x8, tmp);
        }
        bin[g] = (g < 2) ? s * (bias[col] + bias[N3H + col]) : s * bias[col];
    }
    brec2 = SCL2 * bias[N3H + (16 + w) * 16 + m];

    // XOR-swizzled h LDS offsets (ushort units)
    int hro[4], hwo[4];
#pragma unroll
    for (int k = 0; k < 4; ++k) hro[k] = m * HSW + (((4 * k + q) ^ (m & 7)) * 8);
#pragma unroll
    for (int i = 0; i < 4; ++i) {
        const int row = 4 * q + i;
        hwo[i] = row * HSW + (((2 * w + (m >> 3)) ^ (row & 7)) * 8) + (m & 7);
    }

    // per-lane x slice: row b0+m, cols 32k+8q+0..7 (k=0,1) -> 4 dwordx4
    const float* xlane = inputs + ((size_t)(b0 + m) * T_SEQ) * 65 + 8 * q;
    auto ldx = [&](int t, f32x4u* R) {
        const float* p = xlane + (size_t)t * 65;
        R[0] = *(const f32x4u*)p;
        R[1] = *(const f32x4u*)(p + 4);
        R[2] = *(const f32x4u*)(p + 32);
        R[3] = *(const f32x4u*)(p + 36);
    };
    // convert 16 floats -> 2 A-fragments (8 v_perm, truncating)
    auto mkfrag = [&](const f32x4u* R, bf16x8* xa) {
#pragma unroll
        for (int k = 0; k < 2; ++k) {
            u32x4 p;
            p[0] = pk_trunc(R[2 * k][0], R[2 * k][1]);
            p[1] = pk_trunc(R[2 * k][2], R[2 * k][3]);
            p[2] = pk_trunc(R[2 * k + 1][0], R[2 * k + 1][1]);
            p[3] = pk_trunc(R[2 * k + 1][2], R[2 * k + 1][3]);
            xa[k] = __builtin_bit_cast(bf16x8, p);
        }
    };

    // zero h(0)
    {
        unsigned int* p = (unsigned int*)hb[0];
        for (int i = tid; i < 16 * HSW / 2; i += 512) p[i] = 0;
    }

    // pre-loop: load x(0), x(1); compute xw(0)
    f32x4u R0[4], R1[4];
    ldx(0, R0);
    ldx(1, R1);
    f32x4 xwA[3], xwB[3];
    {
        bf16x8 xa[2];
        mkfrag(R0, xa);
#pragma unroll
        for (int g = 0; g < 3; ++g) {
            f32x4 acc = { bin[g], bin[g], bin[g], bin[g] };
            acc = __builtin_amdgcn_mfma_f32_16x16x32_bf16(xa[0], wxB[g][0], acc, 0, 0, 0);
            acc = __builtin_amdgcn_mfma_f32_16x16x32_bf16(xa[1], wxB[g][1], acc, 0, 0, 0);
            xwA[g] = acc;
        }
    }
    lds_barrier();   // h(0) zeros visible

    f32x4 hreg = { 0.f, 0.f, 0.f, 0.f };

    // one step: Rload gets x(t+2); Rconv (holds x(t+1)) is converted -> xw_next
    auto step = [&](int t, f32x4u* Rload, f32x4u* Rconv,
                    f32x4* xw_cur, f32x4* xw_next,
                    const unsigned short* hcur, unsigned short* hnxt,
                    bool first) {
        if (t + 2 < T_SEQ) ldx(t + 2, Rload);

        if (!first) lds_barrier();

        // h fragments
        bf16x8 ha[4];
#pragma unroll
        for (int k = 0; k < 4; ++k) ha[k] = ld8(&hcur[hro[k]]);

        // rec GEMM: 4-deep chains, C seeded with xw (z,r) / brec2 (hh)
        f32x4 racc[3];
#pragma unroll
        for (int g = 0; g < 3; ++g) {
            f32x4 acc = (g < 2) ? xw_cur[g] : f32x4{ brec2, brec2, brec2, brec2 };
#pragma unroll
            for (int k = 0; k < 4; ++k)
                acc = __builtin_amdgcn_mfma_f32_16x16x32_bf16(ha[k], whB[g][k], acc, 0, 0, 0);
            racc[g] = acc;
        }

        // xw(t+1): independent work between rec issue and gate use
        if (t + 1 < T_SEQ) {
            bf16x8 xa[2];
            mkfrag(Rconv, xa);
#pragma unroll
            for (int g = 0; g < 3; ++g) {
                f32x4 acc = { bin[g], bin[g], bin[g], bin[g] };
                acc = __builtin_amdgcn_mfma_f32_16x16x32_bf16(xa[0], wxB[g][0], acc, 0, 0, 0);
                acc = __builtin_amdgcn_mfma_f32_16x16x32_bf16(xa[1], wxB[g][1], acc, 0, 0, 0);
                xw_next[g] = acc;
            }
        }

        // gates: racc[0/1] are complete prescaled pre-activations
        f32x4 hnew;
#pragma unroll
        for (int i = 0; i < 4; ++i) {
            const float ea = __builtin_amdgcn_exp2f(racc[0][i]);
            const float eb = __builtin_amdgcn_exp2f(racc[1][i]);
            const float Pa = 1.0f + ea, Pb = 1.0f + eb;
            const float D  = __builtin_amdgcn_rcpf(Pa * Pb);
            const float z  = Pb * D;
            const float r  = Pa * D;
            const float u  = fmaf(r, racc[2][i], xw_cur[2][i]);
            const float ec = __builtin_amdgcn_exp2f(u);
            const float hh = fmaf(-2.0f, __builtin_amdgcn_rcpf(1.0f + ec), 1.0f);
            hnew[i] = fmaf(z, hreg[i] - hh, hh);
        }
        hreg = hnew;

        // write h(t+1) (RNE, swizzled b16 scatter)
#pragma unroll
        for (int i = 0; i < 4; ++i) hnxt[hwo[i]] = f2bf(hnew[i]);
    };

    step(0, R0, R1, xwA, xwB, hb[0], hb[1], true);
    for (int t = 1; t < T_SEQ - 1; t += 2) {
        step(t,     R1, R0, xwB, xwA, hb[1], hb[0], false);
        step(t + 1, R0, R1, xwA, xwB, hb[0], hb[1], false);
    }
    step(T_SEQ - 1, R1, R0, xwB, xwA, hb[1], hb[0], false);

    // ---- fused tail: +W_state, w1/ReLU/BN, w2 ----
#pragma unroll
    for (int i = 0; i < 4; ++i)
        hf[4 * q + i][16 * w + m] = hreg[i];
    __syncthreads();

    {
        const int row = tid >> 5;
        const int c0  = (tid & 31) * 4;
        const float sf = inputs[((size_t)(b0 + row) * T_SEQ + (T_SEQ - 1)) * 65 + 64];
        int si = (int)sf;
        si = si < 0 ? 0 : (si > 2 ? 2 : si);
#pragma unroll
        for (int c = 0; c < 4; ++c)
            hf[row][c0 + c] += W_state[si * H_DIM + c0 + c];
    }
    __syncthreads();

    {
        const int row = tid >> 5;
        const int jj  = (tid & 31) * 2;
        f32x2 acc = { b1[jj], b1[jj + 1] };
        for (int k = 0; k < H_DIM; ++k) {
            const float hv = hf[row][k];
            const f32x2 wv = *(const f32x2*)(w1 + k * 64 + jj);
            acc[0] = fmaf(hv, wv[0], acc[0]);
            acc[1] = fmaf(hv, wv[1], acc[1]);
        }
        float v = 0.0f;
#pragma unroll
        for (int ii = 0; ii < 2; ++ii) {
            const int j = jj + ii;
            float a = fmaxf(acc[ii], 0.0f);
            a = (a - mean[j]) * rsqrtf(var[j] + 1e-3f) * gamma[j] + beta[j];
            v = fmaf(a, w2[j], v);
        }
        v += __shfl_down(v, 16);
        v += __shfl_down(v, 8);
        v += __shfl_down(v, 4);
        v += __shfl_down(v, 2);
        v += __shfl_down(v, 1);
        if ((tid & 31) == 0) out[b0 + row] = v + b2[0];
    }
}

extern "C" void kernel_launch(void* const* d_in, const int* in_sizes, int n_in,
                              void* d_out, int out_size, void* d_ws, size_t ws_size,
                              hipStream_t stream) {
    (void)in_sizes; (void)n_in; (void)out_size; (void)d_ws; (void)ws_size;
    const float* inputs  = (const float*)d_in[0];
    const float* Wx      = (const float*)d_in[1];
    const float* Wh      = (const float*)d_in[2];
    const float* bias    = (const float*)d_in[3];
    const float* W_state = (const float*)d_in[4];
    const float* w1      = (const float*)d_in[5];
    const float* b1      = (const float*)d_in[6];
    const float* gamma   = (const float*)d_in[7];
    const float* beta    = (const float*)d_in[8];
    const float* mean    = (const float*)d_in[9];
    const float* var     = (const float*)d_in[10];
    const float* w2      = (const float*)d_in[11];
    const float* b2      = (const float*)d_in[12];
    float* out = (float*)d_out;

    gru_fused<<<32, 512, 0, stream>>>(inputs, Wx, Wh, bias, W_state, w1, b1,
                                      gamma, beta, mean, var, w2, b2, out);
}